// Round 6
// baseline (1097.186 us; speedup 1.0000x reference)
//
#include <hip/hip_runtime.h>
#include <hip/hip_bf16.h>
#include <math.h>

// Problem constants (B=1)
#define NW   162
#define WS   256
#define NH   8
#define HD   64
#define CC   512
#define NTOK 41472      // NW*WS
#define HID  2048

typedef __bf16 bf16x8 __attribute__((ext_vector_type(8)));
typedef float  floatx4 __attribute__((ext_vector_type(4)));

__device__ __forceinline__ void gload_lds16(const __bf16* g, __bf16* l) {
    __builtin_amdgcn_global_load_lds((const __attribute__((address_space(1))) void*)g,
                                     (__attribute__((address_space(3))) void*)l,
                                     16, 0, 0);
}
__device__ __forceinline__ float fast_rcp(float x) { return __builtin_amdgcn_rcpf(x); }

#define GBAR()  __builtin_amdgcn_s_barrier()
#define VMW(N)  asm volatile("s_waitcnt vmcnt(" #N ")" ::: "memory")
#define LGKM0() asm volatile("s_waitcnt lgkmcnt(0)" ::: "memory")
#define SCHED0() __builtin_amdgcn_sched_barrier(0)

// ---------------------------------------------------------------- perm build
// Any consistent intra-window order is exact (attention is permutation-
// equivariant within a window; output scattered back through perm).
__global__ __launch_bounds__(256)
void build_perm_atomic(const int* __restrict__ wid, int* __restrict__ perm,
                       int* __restrict__ counters) {
    const int i = blockIdx.x * 256 + threadIdx.x;
    const int w = wid[i];
    const int r = atomicAdd(&counters[w], 1);
    perm[w * WS + r] = i;
}

// ------------------------------------------------------- weight transpose
__global__ void transpose_bf16(const float* __restrict__ in,
                               __bf16* __restrict__ out, int K, int N) {
    int idx = blockIdx.x * 256 + threadIdx.x;
    if (idx >= K * N) return;
    int n = idx / K, k = idx - n * K;
    out[idx] = (__bf16)in[(size_t)k * N + n];
}

// ---------------------------------------------------------------- LN kernels
__global__ __launch_bounds__(64)
void ln1_gather(const float* __restrict__ x, const int* __restrict__ perm,
                const float* __restrict__ g, const float* __restrict__ b,
                __bf16* __restrict__ h) {
    const int j = blockIdx.x, lane = threadIdx.x;
    const int orig = perm[j];
    const float4* xp = (const float4*)(x + (size_t)orig * CC);
    float4 a0 = xp[lane * 2 + 0], a1 = xp[lane * 2 + 1];
    float s  = a0.x + a0.y + a0.z + a0.w + a1.x + a1.y + a1.z + a1.w;
    float sq = a0.x*a0.x + a0.y*a0.y + a0.z*a0.z + a0.w*a0.w
             + a1.x*a1.x + a1.y*a1.y + a1.z*a1.z + a1.w*a1.w;
#pragma unroll
    for (int o = 32; o; o >>= 1) { s += __shfl_xor(s, o); sq += __shfl_xor(sq, o); }
    const float m  = s * (1.f / CC);
    const float rs = rsqrtf(sq * (1.f / CC) - m * m + 1e-5f);
    const float4* g4 = (const float4*)g;  const float4* b4 = (const float4*)b;
    float4 g0 = g4[lane*2+0], g1 = g4[lane*2+1], bb0 = b4[lane*2+0], bb1 = b4[lane*2+1];
    bf16x8 o8;
    o8[0] = (__bf16)((a0.x - m) * rs * g0.x + bb0.x);
    o8[1] = (__bf16)((a0.y - m) * rs * g0.y + bb0.y);
    o8[2] = (__bf16)((a0.z - m) * rs * g0.z + bb0.z);
    o8[3] = (__bf16)((a0.w - m) * rs * g0.w + bb0.w);
    o8[4] = (__bf16)((a1.x - m) * rs * g1.x + bb1.x);
    o8[5] = (__bf16)((a1.y - m) * rs * g1.y + bb1.y);
    o8[6] = (__bf16)((a1.z - m) * rs * g1.z + bb1.z);
    o8[7] = (__bf16)((a1.w - m) * rs * g1.w + bb1.w);
    *(bf16x8*)(h + (size_t)j * CC + lane * 8) = o8;
}

// LN over xout (which already holds x + proj residual), writes bf16 h2.
__global__ __launch_bounds__(64)
void ln2_only(const float* __restrict__ x, const float* __restrict__ g,
              const float* __restrict__ b, __bf16* __restrict__ h2) {
    const int i = blockIdx.x, lane = threadIdx.x;
    const float4* xp = (const float4*)(x + (size_t)i * CC);
    float4 a0 = xp[lane*2+0], a1 = xp[lane*2+1];
    float s  = a0.x + a0.y + a0.z + a0.w + a1.x + a1.y + a1.z + a1.w;
    float sq = a0.x*a0.x + a0.y*a0.y + a0.z*a0.z + a0.w*a0.w
             + a1.x*a1.x + a1.y*a1.y + a1.z*a1.z + a1.w*a1.w;
#pragma unroll
    for (int o = 32; o; o >>= 1) { s += __shfl_xor(s, o); sq += __shfl_xor(sq, o); }
    const float m  = s * (1.f / CC);
    const float rs = rsqrtf(sq * (1.f / CC) - m * m + 1e-5f);
    const float4* g4 = (const float4*)g;  const float4* b4 = (const float4*)b;
    float4 g0 = g4[lane*2+0], g1 = g4[lane*2+1], bb0 = b4[lane*2+0], bb1 = b4[lane*2+1];
    bf16x8 o8;
    o8[0] = (__bf16)((a0.x - m) * rs * g0.x + bb0.x);
    o8[1] = (__bf16)((a0.y - m) * rs * g0.y + bb0.y);
    o8[2] = (__bf16)((a0.z - m) * rs * g0.z + bb0.z);
    o8[3] = (__bf16)((a0.w - m) * rs * g0.w + bb0.w);
    o8[4] = (__bf16)((a1.x - m) * rs * g1.x + bb1.x);
    o8[5] = (__bf16)((a1.y - m) * rs * g1.y + bb1.y);
    o8[6] = (__bf16)((a1.z - m) * rs * g1.z + bb1.z);
    o8[7] = (__bf16)((a1.w - m) * rs * g1.w + bb1.w);
    *(bf16x8*)(h2 + (size_t)i * CC + lane * 8) = o8;
}

// ---------------------------------------------------------------- GEMM 256x256, B-from-L2
// LDS-roofline redesign.  The old structure moved 256 KB of LDS traffic per
// 8.4 MFLOP K-tile (A-frags read x4 across wn-groups, B x2, +staging writes)
// = 32.8 FLOP/LDS-byte -> ~28% MfmaUtil ceiling at 85 B/cy/CU; measured 24.5%
// (86% of that ceiling).  B is always an L2-resident weight panel (<=2 MB per
// XCD), so B fragments are now loaded DIRECTLY from global into registers
// (double-buffered one K-tile ahead; L2 latency hides under ~2 phases), and
// LDS carries only A: 160 KB/tile -> 52.5 FLOP/LDS-byte (ceiling x1.6).
// 8 waves (2M x 4N), BK=64, A double-buffered in 32 KB of LDS (epilogue
// C-tile reuses the full 128 KB).  2 barriers/K-tile.
// vmcnt bookkeeping (verified by induction; per-wave issue order per tile t:
// ph0: bn0 4 glob, ph1: bn1 4 glob, ph2: A1(t+1) 2 gload_lds, ph3: A0(t+2) 2):
//   entering ph0(t): 14 outstanding [A0(t) 2, bc0 4, bc1 4, A1(t) 2, A0(t+1) 2]
//   ph0 VMW(8)  -> completes A0(t)+bc0; GBAR publishes A0(t); read af0
//   ph1 VMW(8)  -> completes bc1 (wave-private regs; no barrier needed)
//   ph2 VMW(10) -> completes A1(t); GBAR publishes; read af1
//   ph3: no wait (all operands in regs)
// Final tile drains with VMW(6)/(2)/(0).  Slot-overwrite safety: every stage
// targets rows whose ds_reads retired (LGKM0) before a barrier all waves have
// passed (A1: ph0(t) GBAR covers ph2(t-1) LGKM0; A0: ph2(t) GBAR covers
// ph0(t) LGKM0).  XOR chunk swizzle on A staging source and frag reads —
// conflict-free (SQ_LDS_BANK_CONFLICT == 0 measured).
__device__ __forceinline__ void stage_A(const __bf16* __restrict__ g, int K, int kcol,
                                        __bf16* lds, int h, int tid, int wave) {
    const int sch = ((tid & 7) ^ ((tid >> 3) & 7)) << 3;
#pragma unroll
    for (int j = 0; j < 2; j++) {
        const int rw   = (j * 512 + tid) >> 3;
        const int row  = (rw & 63) + ((rw & 64) << 1) + (h << 6);
        const int rw0  = j * 64 + wave * 8;
        const int row0 = (rw0 & 63) + ((rw0 & 64) << 1) + (h << 6);
        gload_lds16(g + (size_t)row * K + kcol + sch, lds + row0 * 64);
    }
}

__device__ __forceinline__ void load_afr(const __bf16* buf, int wm, int mh,
                                         int lr, int lq, bf16x8 (&af)[4][2]) {
#pragma unroll
    for (int mt = 0; mt < 4; mt++) {
        const __bf16* rp = buf + (wm * 128 + mh * 64 + mt * 16 + lr) * 64;
#pragma unroll
        for (int kk = 0; kk < 2; kk++)
            af[mt][kk] = *(const bf16x8*)(rp + (((kk * 4 + lq) ^ (lr & 7)) << 3));
    }
}

// B fragments straight from global (L2-hit): rows wn*64 + nh*32 + nt*16 + lr,
// k-chunk (kk*4+lq)*8 — same fragment layout the LDS path produced.
__device__ __forceinline__ void loadB_g(const __bf16* __restrict__ gBw, int K, int kcol,
                                        int nh, int lr, int lq, bf16x8 (&bf)[2][2]) {
#pragma unroll
    for (int nt = 0; nt < 2; nt++) {
        const __bf16* rp = gBw + (size_t)(nh * 32 + nt * 16 + lr) * K + kcol + lq * 8;
#pragma unroll
        for (int kk = 0; kk < 2; kk++)
            bf[nt][kk] = *(const bf16x8*)(rp + kk * 32);
    }
}

#define MFMA_QUAD(MH, NH, AF, BF)                                              \
    _Pragma("unroll") for (int kk_ = 0; kk_ < 2; kk_++)                        \
    _Pragma("unroll") for (int mt_ = 0; mt_ < 4; mt_++)                        \
    _Pragma("unroll") for (int nt_ = 0; nt_ < 2; nt_++)                        \
        acc[(MH) * 4 + mt_][(NH) * 2 + nt_] =                                  \
            __builtin_amdgcn_mfma_f32_16x16x32_bf16(                           \
                AF[mt_][kk_], BF[nt_][kk_],                                    \
                acc[(MH) * 4 + mt_][(NH) * 2 + nt_], 0, 0, 0);

// EPI: 0 = +bias -> bf16; 1 = +bias -> f32; 2 = +bias, GELU(logistic) -> bf16;
//      3 = res + acc + bias -> f32 (in-place residual);
//      4 = gathered residual: Cf[perm[row]] = res[perm[row]] + acc + bias.
template <int EPI>
__device__ __forceinline__
void gemm_body(const __bf16* __restrict__ A, const __bf16* __restrict__ Bt,
               const float* __restrict__ bias, const float* __restrict__ res,
               float* __restrict__ Cf, __bf16* __restrict__ Cb,
               int M, int N, int K, const int* __restrict__ prm) {
    __shared__ __bf16 smem[65536];   // A dbuf in first 32 KB; epilogue C-tile = all 128 KB
    __bf16* Ac = smem;
    __bf16* An = smem + 16384;

    const int tid  = threadIdx.x;
    const int wave = tid >> 6;
    const int lane = tid & 63;
    const int wm = wave >> 2, wn = wave & 3;
    const int lr = lane & 15, lq = lane >> 4;

    // bijective XCD-aware swizzle (m204 form; grids here are not all %8==0)
    const int gx  = gridDim.x;
    const int nwg = gx * gridDim.y;
    const int orig = blockIdx.y * gx + blockIdx.x;
    const int q8 = nwg >> 3, r8 = nwg & 7;
    const int xcd = orig & 7, oi = orig >> 3;
    const int wgid = (xcd < r8 ? xcd * (q8 + 1) : r8 * (q8 + 1) + (xcd - r8) * q8) + oi;
    const int bm = wgid / gx, bn = wgid - bm * gx;

    const __bf16* gA  = A  + (size_t)bm * 256 * K;
    const __bf16* gBw = Bt + (size_t)(bn * 256 + wn * 64) * K;  // this wave's B rows
    const int NT = K >> 6;   // even for every GEMM here (8 or 32)

    floatx4 acc[8][4];
#pragma unroll
    for (int i = 0; i < 8; i++)
#pragma unroll
        for (int j = 0; j < 4; j++) acc[i][j] = (floatx4){0.f, 0.f, 0.f, 0.f};

    bf16x8 af[4][2];
    bf16x8 bc0[2][2], bc1[2][2], bn0[2][2], bn1[2][2];

    // prologue — issue order defines the steady-state vmcnt queue:
    // [A0(0) 2, b0(0) 4, b1(0) 4, A1(0) 2, A0(1) 2] = 14 outstanding.
    stage_A(gA, K, 0, Ac, 0, tid, wave);
    loadB_g(gBw, K, 0, 0, lr, lq, bc0);
    loadB_g(gBw, K, 0, 1, lr, lq, bc1);
    stage_A(gA, K, 0, Ac, 1, tid, wave);
    if (NT > 1) stage_A(gA, K, 64, An, 0, tid, wave);

    auto tile_step = [&](int t, bf16x8 (&c0)[2][2], bf16x8 (&c1)[2][2],
                         bf16x8 (&n0)[2][2], bf16x8 (&n1)[2][2]) {
        const int k1 = (t + 1) << 6;
        const bool s = (t + 1 < NT);
        // ---- phase 0: MFMA (mh0, c0).  VMW completes A0(t)+c0; GBAR
        //      publishes A0(t) cross-wave; then af0 reads.
        if (s) { VMW(8); } else { VMW(6); }
        if (s) loadB_g(gBw, K, k1, 0, lr, lq, n0);
        GBAR();
        load_afr(Ac, wm, 0, lr, lq, af);
        LGKM0(); SCHED0();
        __builtin_amdgcn_s_setprio(1);
        MFMA_QUAD(0, 0, af, c0);
        __builtin_amdgcn_s_setprio(0);
        // ---- phase 1: MFMA (mh0, c1).  c1 is wave-private regs: VMW only.
        if (s) { VMW(8); } else { VMW(2); }
        if (s) loadB_g(gBw, K, k1, 1, lr, lq, n1);
        SCHED0();
        __builtin_amdgcn_s_setprio(1);
        MFMA_QUAD(0, 1, af, c1);
        __builtin_amdgcn_s_setprio(0);
        // ---- phase 2: MFMA (mh1, c1).  VMW completes A1(t); stage A1(t+1)
        //      into An (its old contents' reads retired before ph0's GBAR);
        //      GBAR publishes A1(t); af1 reads.
        if (s) { VMW(10); } else { VMW(0); }
        if (s) stage_A(gA, K, k1, An, 1, tid, wave);
        GBAR();
        load_afr(Ac, wm, 1, lr, lq, af);
        LGKM0(); SCHED0();
        __builtin_amdgcn_s_setprio(1);
        MFMA_QUAD(1, 1, af, c1);
        __builtin_amdgcn_s_setprio(0);
        // ---- phase 3: MFMA (mh1, c0) — all operands in regs.  Stage A0(t+2)
        //      into Ac (rows read at ph0(t), retired at its LGKM0, separated
        //      by ph2(t)'s GBAR).
        if (t + 2 < NT) stage_A(gA, K, (t + 2) << 6, Ac, 0, tid, wave);
        __builtin_amdgcn_s_setprio(1);
        MFMA_QUAD(1, 0, af, c0);
        __builtin_amdgcn_s_setprio(0);
        // swap A double buffer
        __bf16* ta = Ac; Ac = An; An = ta;
    };

    // 2-tile unroll with B-register role swap (NT is even) — no copies, so
    // the compiler never forces an early vmcnt on a bn->bc move.
    for (int t = 0; t < NT; t += 2) {
        tile_step(t,     bc0, bc1, bn0, bn1);
        tile_step(t + 1, bn0, bn1, bc0, bc1);
    }

    if constexpr (EPI == 0 || EPI == 2) {
        // repack through LDS (reuse the 128 KiB as a [256][256] bf16 C-tile).
        // Barrier first: waves may drift; some may still read af from smem.
        GBAR();
        __bf16* Ct = smem;
#pragma unroll
        for (int m = 0; m < 8; m++)
#pragma unroll
            for (int n = 0; n < 4; n++) {
                const int col = wn * 64 + n * 16 + lr;
                const float bv = bias[bn * 256 + col];
#pragma unroll
                for (int r = 0; r < 4; r++) {
                    float v = acc[m][n][r] + bv;
                    if constexpr (EPI == 2) {
                        // gelu ~= v * sigmoid(1.702 v); pre-act sigma~0.45 so
                        // logistic-vs-erf error is ~1e-3 after W2 contraction
                        const float e = __expf(v * -1.702f);
                        v = v * fast_rcp(1.f + e);
                    }
                    Ct[(wm * 128 + m * 16 + lq * 4 + r) * 256 + col] = (__bf16)v;
                }
            }
        __syncthreads();
#pragma unroll
        for (int j = 0; j < 16; j++) {
            const int ci = j * 512 + tid;
            const int row = ci >> 5, ch = ci & 31;
            *(bf16x8*)(Cb + (size_t)(bm * 256 + row) * N + bn * 256 + ch * 8) =
                *(const bf16x8*)(Ct + row * 256 + ch * 8);
        }
    } else {
#pragma unroll
        for (int m = 0; m < 8; m++) {
            const int row = bm * 256 + wm * 128 + m * 16 + lq * 4;
            int tok[4];
            if constexpr (EPI == 4) {
#pragma unroll
                for (int r = 0; r < 4; r++) tok[r] = prm[row + r];
            }
#pragma unroll
            for (int n = 0; n < 4; n++) {
                const int col = bn * 256 + wn * 64 + n * 16 + lr;
                const float bv = bias[col];
#pragma unroll
                for (int r = 0; r < 4; r++) {
                    const float v = acc[m][n][r] + bv;
                    if constexpr (EPI == 1) {
                        Cf[(size_t)(row + r) * N + col] = v;
                    } else if constexpr (EPI == 3) {
                        const size_t off = (size_t)(row + r) * N + col;
                        Cf[off] = res[off] + v;
                    } else {  // EPI == 4: scatter residual through perm
                        const size_t off = (size_t)tok[r] * N + col;
                        Cf[off] = res[off] + v;
                    }
                }
            }
        }
    }
}

// Distinct names per stage so the profiler's top-5 shows the true split.
__global__ __launch_bounds__(512, 2)
void gemm_qkv(const __bf16* __restrict__ A, const __bf16* __restrict__ Bt,
              const float* __restrict__ bias, __bf16* __restrict__ Cb, int N, int K) {
    gemm_body<0>(A, Bt, bias, nullptr, nullptr, Cb, NTOK, N, K, nullptr);
}
__global__ __launch_bounds__(512, 2)
void gemm_proj(const __bf16* __restrict__ A, const __bf16* __restrict__ Bt,
               const float* __restrict__ bias, const float* __restrict__ res,
               float* __restrict__ Cf, const int* __restrict__ prm, int N, int K) {
    gemm_body<4>(A, Bt, bias, res, Cf, nullptr, NTOK, N, K, prm);
}
__global__ __launch_bounds__(512, 2)
void gemm_ffn1(const __bf16* __restrict__ A, const __bf16* __restrict__ Bt,
               const float* __restrict__ bias, __bf16* __restrict__ Cb, int N, int K) {
    gemm_body<2>(A, Bt, bias, nullptr, nullptr, Cb, NTOK, N, K, nullptr);
}
__global__ __launch_bounds__(512, 2)
void gemm_ffn2(const __bf16* __restrict__ A, const __bf16* __restrict__ Bt,
               const float* __restrict__ bias, const float* __restrict__ res,
               float* __restrict__ Cf, int N, int K) {
    gemm_body<3>(A, Bt, bias, res, Cf, nullptr, NTOK, N, K, nullptr);
}

// ---------------------------------------------------------------- attention (MFMA)
// One block per (window, head), 4 waves x 64 q-rows. ONE barrier total (after
// V staging): pbuf is wave-private and cross-lane LDS traffic within a wave
// is ordered by lgkmcnt — no __syncthreads needed in the K-loop or epilogue.
// V is stored TRANSPOSED in LDS with an XOR swizzle on the key-block index so
// PV B-frags are 4x ds_read_b128 per kt (uniform bank spread) instead of 32
// scalar reads. K fragments are software-prefetched one kt ahead.
__global__ __launch_bounds__(256)
void attn_mfma(const __bf16* __restrict__ qkv, __bf16* __restrict__ aout,
               const float* __restrict__ rel_bias) {
    __shared__ __bf16 vsT[HD * WS];      // [d][key-swizzled], 32 KB
    __shared__ __bf16 pbuf[4][64][34];   // wave-private P tile
    const int w = blockIdx.x, h = blockIdx.y;
    const int tid = threadIdx.x;
    const int wave = tid >> 6, lane = tid & 63;
    const int lr = lane & 15, lq = lane >> 4;
    const size_t base = (size_t)w * (WS * 1536) + h * 64;

    // stage V transposed: coalesced global bf16x8 reads, scalar swizzled LDS writes
    for (int c = tid; c < WS * 8; c += 256) {
        const int key = c >> 3, d8 = c & 7;
        bf16x8 vv = *(const bf16x8*)(qkv + base + 1024 + (size_t)key * 1536 + d8 * 8);
#pragma unroll
        for (int jj = 0; jj < 8; jj++) {
            const int d = d8 * 8 + jj;
            vsT[d * WS + (((key >> 3) ^ (d & 31)) << 3) + (key & 7)] = vv[jj];
        }
    }

    const int q0 = wave * 64;
    bf16x8 qf[4][2];
#pragma unroll
    for (int mt = 0; mt < 4; mt++)
#pragma unroll
        for (int kk = 0; kk < 2; kk++)
            qf[mt][kk] = *(const bf16x8*)(qkv + base +
                (size_t)(q0 + mt * 16 + lr) * 1536 + kk * 32 + lq * 8);

    __syncthreads();   // the only block-wide barrier

    floatx4 o[4][4];
    float lsum[4][4];
#pragma unroll
    for (int mt = 0; mt < 4; mt++)
#pragma unroll
        for (int dt = 0; dt < 4; dt++) o[mt][dt] = (floatx4){0.f, 0.f, 0.f, 0.f};
#pragma unroll
    for (int mt = 0; mt < 4; mt++)
#pragma unroll
        for (int r = 0; r < 4; r++) lsum[mt][r] = 0.f;

    const float sc = 0.125f * 1.44269504089f;
    const float bb = rel_bias[h] * 1.44269504089f;
    const __bf16* kp0 = qkv + base + 512;

    // prefetch kt=0 K-frags
    bf16x8 kc[2][2];
#pragma unroll
    for (int nt = 0; nt < 2; nt++) {
        const __bf16* kp = kp0 + (size_t)(nt * 16 + lr) * 1536 + lq * 8;
        kc[nt][0] = *(const bf16x8*)(kp);
        kc[nt][1] = *(const bf16x8*)(kp + 32);
    }

    for (int kt = 0; kt < 8; kt++) {
        const int kbase = kt * 32;
        bf16x8 kn[2][2];
        if (kt < 7) {
#pragma unroll
            for (int nt = 0; nt < 2; nt++) {
                const __bf16* kp = kp0 + (size_t)(kbase + 32 + nt * 16 + lr) * 1536 + lq * 8;
                kn[nt][0] = *(const bf16x8*)(kp);
                kn[nt][1] = *(const bf16x8*)(kp + 32);
            }
        }
        floatx4 s[4][2];
#pragma unroll
        for (int mt = 0; mt < 4; mt++)
#pragma unroll
            for (int nt = 0; nt < 2; nt++) s[mt][nt] = (floatx4){0.f, 0.f, 0.f, 0.f};
#pragma unroll
        for (int nt = 0; nt < 2; nt++)
#pragma unroll
            for (int mt = 0; mt < 4; mt++) {
                s[mt][nt] = __builtin_amdgcn_mfma_f32_16x16x32_bf16(qf[mt][0], kc[nt][0], s[mt][nt], 0, 0, 0);
                s[mt][nt] = __builtin_amdgcn_mfma_f32_16x16x32_bf16(qf[mt][1], kc[nt][1], s[mt][nt], 0, 0, 0);
            }
#pragma unroll
        for (int mt = 0; mt < 4; mt++)
#pragma unroll
            for (int nt = 0; nt < 2; nt++)
#pragma unroll
                for (int r = 0; r < 4; r++) {
                    float e = exp2f(s[mt][nt][r] * sc + bb);
                    lsum[mt][r] += e;
                    pbuf[wave][mt * 16 + lq * 4 + r][nt * 16 + lr] = (__bf16)e;
                }
        // V B-frags: vf[dt][j] = V[kbase+lq*8+j][dt*16+lr] via swizzled vsT
        bf16x8 vf[4];
#pragma unroll
        for (int dt = 0; dt < 4; dt++) {
            const int d = dt * 16 + lr;
            vf[dt] = *(const bf16x8*)(vsT + d * WS +
                                      (((kt * 4 + lq) ^ (d & 31)) << 3));
        }
#pragma unroll
        for (int mt = 0; mt < 4; mt++) {
            bf16x8 pf = *(const bf16x8*)(&pbuf[wave][mt * 16 + lr][lq * 8]);
#pragma unroll
            for (int dt = 0; dt < 4; dt++)
                o[mt][dt] = __builtin_amdgcn_mfma_f32_16x16x32_bf16(pf, vf[dt], o[mt][dt], 0, 0, 0);
        }
#pragma unroll
        for (int nt = 0; nt < 2; nt++) { kc[nt][0] = kn[nt][0]; kc[nt][1] = kn[nt][1]; }
    }

#pragma unroll
    for (int mt = 0; mt < 4; mt++)
#pragma unroll
        for (int r = 0; r < 4; r++) {
            float v = lsum[mt][r];
            v += __shfl_xor(v, 1); v += __shfl_xor(v, 2);
            v += __shfl_xor(v, 4); v += __shfl_xor(v, 8);
            lsum[mt][r] = fast_rcp(v);
        }

    // scale + repack through wave-private pbuf (no barriers needed)
#pragma unroll
    for (int dh = 0; dh < 2; dh++) {
#pragma unroll
        for (int mt = 0; mt < 4; mt++)
#pragma unroll
            for (int dt = 0; dt < 2; dt++)
#pragma unroll
                for (int r = 0; r < 4; r++)
                    pbuf[wave][mt * 16 + lq * 4 + r][dt * 16 + lr] =
                        (__bf16)(o[mt][dh * 2 + dt][r] * lsum[mt][r]);
#pragma unroll
        for (int it = 0; it < 4; it++) {
            const int c = it * 64 + lane;
            const int row = c >> 2, seg = c & 3;
            bf16x8 val = *(const bf16x8*)(&pbuf[wave][row][seg * 8]);
            *(bf16x8*)(aout + (size_t)(w * WS + q0 + row) * CC + h * 64 + dh * 32 + seg * 8) = val;
        }
    }
}

// ---------------------------------------------------------------- launch
extern "C" void kernel_launch(void* const* d_in, const int* in_sizes, int n_in,
                              void* d_out, int out_size, void* d_ws, size_t ws_size,
                              hipStream_t stream) {
    const float* x      = (const float*)d_in[0];
    const float* mesh   = (const float*)d_in[1];
    const float* ln1_g  = (const float*)d_in[2];
    const float* ln1_b  = (const float*)d_in[3];
    const float* qkv_w  = (const float*)d_in[4];
    const float* qkv_b  = (const float*)d_in[5];
    const float* rel_b  = (const float*)d_in[6];
    const float* proj_w = (const float*)d_in[7];
    const float* proj_b = (const float*)d_in[8];
    const float* ln2_g  = (const float*)d_in[9];
    const float* ln2_b  = (const float*)d_in[10];
    const float* w1     = (const float*)d_in[11];
    const float* b1     = (const float*)d_in[12];
    const float* w2     = (const float*)d_in[13];
    const float* b2     = (const float*)d_in[14];
    const int*   wid    = (const int*)d_in[15];

    char* ws = (char*)d_ws;
    int*    perm  = (int*)(ws + 0);
    __bf16* wqkv  = (__bf16*)(ws + 331776);
    __bf16* wproj = (__bf16*)(ws + 1904640);
    __bf16* w1t   = (__bf16*)(ws + 2428928);
    __bf16* w2t   = (__bf16*)(ws + 4526080);
    const size_t BB = 6623232;
    __bf16* hln1 = (__bf16*)(ws + BB);
    __bf16* qkv  = (__bf16*)(ws + BB + 42467328);
    __bf16* aout = (__bf16*)(ws + BB + 169869312);
    __bf16* h2   = (__bf16*)(ws + BB + 84934656);
    __bf16* f1   = (__bf16*)(ws + BB + 127401984);
    float*  xout = (float*)d_out;
    int*    counters = (int*)aout;   // dead region until attention writes aout

    hipMemsetAsync(counters, 0, NW * sizeof(int), stream);
    build_perm_atomic<<<NTOK / 256, 256, 0, stream>>>(wid, perm, counters);

    transpose_bf16<<<(512 * 1536 + 255) / 256, 256, 0, stream>>>(qkv_w, wqkv, 512, 1536);
    transpose_bf16<<<(512 * 512 + 255) / 256, 256, 0, stream>>>(proj_w, wproj, 512, 512);
    transpose_bf16<<<(512 * 2048 + 255) / 256, 256, 0, stream>>>(w1, w1t, 512, 2048);
    transpose_bf16<<<(2048 * 512 + 255) / 256, 256, 0, stream>>>(w2, w2t, 2048, 512);

    ln1_gather<<<NTOK, 64, 0, stream>>>(x, perm, ln1_g, ln1_b, hln1);

    gemm_qkv<<<dim3(1536 / 256, NTOK / 256), 512, 0, stream>>>(
        hln1, wqkv, qkv_b, qkv, 1536, 512);

    attn_mfma<<<dim3(NW, NH), 256, 0, stream>>>(qkv, aout, rel_b);

    // proj with fused gathered residual: xout[perm[row]] = x[perm[row]] + out
    gemm_proj<<<dim3(512 / 256, NTOK / 256), 512, 0, stream>>>(
        aout, wproj, proj_b, x, xout, perm, 512, 512);

    ln2_only<<<NTOK, 64, 0, stream>>>(xout, ln2_g, ln2_b, h2);

    gemm_ffn1<<<dim3(2048 / 256, NTOK / 256), 512, 0, stream>>>(
        h2, w1t, b1, f1, 2048, 512);

    gemm_ffn2<<<dim3(512 / 256, NTOK / 256), 512, 0, stream>>>(
        f1, w2t, b2, xout, xout, 512, 2048);

    hipMemcpyAsync((char*)d_out + (size_t)NTOK * CC * 4, mesh,
                   (size_t)NTOK * 3 * 4, hipMemcpyDeviceToDevice, stream);
}

// Round 7
// 716.212 us; speedup vs baseline: 1.5319x; 1.5319x over previous
//
#include <hip/hip_runtime.h>
#include <hip/hip_bf16.h>
#include <math.h>

// Problem constants (B=1)
#define NW   162
#define WS   256
#define NH   8
#define HD   64
#define CC   512
#define NTOK 41472      // NW*WS
#define HID  2048

typedef __bf16 bf16x8 __attribute__((ext_vector_type(8)));
typedef float  floatx4 __attribute__((ext_vector_type(4)));

__device__ __forceinline__ void gload_lds16(const __bf16* g, __bf16* l) {
    __builtin_amdgcn_global_load_lds((const __attribute__((address_space(1))) void*)g,
                                     (__attribute__((address_space(3))) void*)l,
                                     16, 0, 0);
}
__device__ __forceinline__ float fast_rcp(float x) { return __builtin_amdgcn_rcpf(x); }

#define GBAR()  __builtin_amdgcn_s_barrier()
#define VMW(N)  asm volatile("s_waitcnt vmcnt(" #N ")" ::: "memory")
#define LGKM0() asm volatile("s_waitcnt lgkmcnt(0)" ::: "memory")
#define SCHED0() __builtin_amdgcn_sched_barrier(0)

// ---------------------------------------------------------------- perm build
__global__ __launch_bounds__(256)
void build_perm_atomic(const int* __restrict__ wid, int* __restrict__ perm,
                       int* __restrict__ counters) {
    const int i = blockIdx.x * 256 + threadIdx.x;
    const int w = wid[i];
    const int r = atomicAdd(&counters[w], 1);
    perm[w * WS + r] = i;
}

// ------------------------------------------------------- weight transpose
__global__ void transpose_bf16(const float* __restrict__ in,
                               __bf16* __restrict__ out, int K, int N) {
    int idx = blockIdx.x * 256 + threadIdx.x;
    if (idx >= K * N) return;
    int n = idx / K, k = idx - n * K;
    out[idx] = (__bf16)in[(size_t)k * N + n];
}

// ---------------------------------------------------------------- LN kernels
__global__ __launch_bounds__(64)
void ln1_gather(const float* __restrict__ x, const int* __restrict__ perm,
                const float* __restrict__ g, const float* __restrict__ b,
                __bf16* __restrict__ h) {
    const int j = blockIdx.x, lane = threadIdx.x;
    const int orig = perm[j];
    const float4* xp = (const float4*)(x + (size_t)orig * CC);
    float4 a0 = xp[lane * 2 + 0], a1 = xp[lane * 2 + 1];
    float s  = a0.x + a0.y + a0.z + a0.w + a1.x + a1.y + a1.z + a1.w;
    float sq = a0.x*a0.x + a0.y*a0.y + a0.z*a0.z + a0.w*a0.w
             + a1.x*a1.x + a1.y*a1.y + a1.z*a1.z + a1.w*a1.w;
#pragma unroll
    for (int o = 32; o; o >>= 1) { s += __shfl_xor(s, o); sq += __shfl_xor(sq, o); }
    const float m  = s * (1.f / CC);
    const float rs = rsqrtf(sq * (1.f / CC) - m * m + 1e-5f);
    const float4* g4 = (const float4*)g;  const float4* b4 = (const float4*)b;
    float4 g0 = g4[lane*2+0], g1 = g4[lane*2+1], bb0 = b4[lane*2+0], bb1 = b4[lane*2+1];
    bf16x8 o8;
    o8[0] = (__bf16)((a0.x - m) * rs * g0.x + bb0.x);
    o8[1] = (__bf16)((a0.y - m) * rs * g0.y + bb0.y);
    o8[2] = (__bf16)((a0.z - m) * rs * g0.z + bb0.z);
    o8[3] = (__bf16)((a0.w - m) * rs * g0.w + bb0.w);
    o8[4] = (__bf16)((a1.x - m) * rs * g1.x + bb1.x);
    o8[5] = (__bf16)((a1.y - m) * rs * g1.y + bb1.y);
    o8[6] = (__bf16)((a1.z - m) * rs * g1.z + bb1.z);
    o8[7] = (__bf16)((a1.w - m) * rs * g1.w + bb1.w);
    *(bf16x8*)(h + (size_t)j * CC + lane * 8) = o8;
}

// LN over xout (which already holds x + proj residual), writes bf16 h2.
__global__ __launch_bounds__(64)
void ln2_only(const float* __restrict__ x, const float* __restrict__ g,
              const float* __restrict__ b, __bf16* __restrict__ h2) {
    const int i = blockIdx.x, lane = threadIdx.x;
    const float4* xp = (const float4*)(x + (size_t)i * CC);
    float4 a0 = xp[lane*2+0], a1 = xp[lane*2+1];
    float s  = a0.x + a0.y + a0.z + a0.w + a1.x + a1.y + a1.z + a1.w;
    float sq = a0.x*a0.x + a0.y*a0.y + a0.z*a0.z + a0.w*a0.w
             + a1.x*a1.x + a1.y*a1.y + a1.z*a1.z + a1.w*a1.w;
#pragma unroll
    for (int o = 32; o; o >>= 1) { s += __shfl_xor(s, o); sq += __shfl_xor(sq, o); }
    const float m  = s * (1.f / CC);
    const float rs = rsqrtf(sq * (1.f / CC) - m * m + 1e-5f);
    const float4* g4 = (const float4*)g;  const float4* b4 = (const float4*)b;
    float4 g0 = g4[lane*2+0], g1 = g4[lane*2+1], bb0 = b4[lane*2+0], bb1 = b4[lane*2+1];
    bf16x8 o8;
    o8[0] = (__bf16)((a0.x - m) * rs * g0.x + bb0.x);
    o8[1] = (__bf16)((a0.y - m) * rs * g0.y + bb0.y);
    o8[2] = (__bf16)((a0.z - m) * rs * g0.z + bb0.z);
    o8[3] = (__bf16)((a0.w - m) * rs * g0.w + bb0.w);
    o8[4] = (__bf16)((a1.x - m) * rs * g1.x + bb1.x);
    o8[5] = (__bf16)((a1.y - m) * rs * g1.y + bb1.y);
    o8[6] = (__bf16)((a1.z - m) * rs * g1.z + bb1.z);
    o8[7] = (__bf16)((a1.w - m) * rs * g1.w + bb1.w);
    *(bf16x8*)(h2 + (size_t)i * CC + lane * 8) = o8;
}

// ---------------------------------------------------------------- GEMM staging/frag helpers
// XOR chunk swizzle (chunk ^= row&7) on staging source and frag reads —
// conflict-free (SQ_LDS_BANK_CONFLICT == 0 measured).
__device__ __forceinline__ void stage_A(const __bf16* __restrict__ g, int K, int kcol,
                                        __bf16* lds, int h, int tid, int wave) {
    const int sch = ((tid & 7) ^ ((tid >> 3) & 7)) << 3;
#pragma unroll
    for (int j = 0; j < 2; j++) {
        const int rw   = (j * 512 + tid) >> 3;
        const int row  = (rw & 63) + ((rw & 64) << 1) + (h << 6);
        const int rw0  = j * 64 + wave * 8;
        const int row0 = (rw0 & 63) + ((rw0 & 64) << 1) + (h << 6);
        gload_lds16(g + (size_t)row * K + kcol + sch, lds + row0 * 64);
    }
}
// 128-row A tile (16 KB in one call; rows 0..127 linear)
__device__ __forceinline__ void stage_A128(const __bf16* __restrict__ g, int K, int kcol,
                                           __bf16* lds, int tid, int wave) {
    const int sch = ((tid & 7) ^ ((tid >> 3) & 7)) << 3;
#pragma unroll
    for (int j = 0; j < 2; j++) {
        const int row  = (j * 512 + tid) >> 3;        // 0..127
        const int row0 = j * 64 + wave * 8;
        gload_lds16(g + (size_t)row * K + kcol + sch, lds + row0 * 64);
    }
}
__device__ __forceinline__ void stage_B(const __bf16* __restrict__ g, int K, int kcol,
                                        __bf16* lds, int h, int tid, int wave) {
    const int sch = ((tid & 7) ^ ((tid >> 3) & 7)) << 3;
#pragma unroll
    for (int j = 0; j < 2; j++) {
        const int rw   = (j * 512 + tid) >> 3;
        const int row  = (rw & 31) + ((rw >> 5) << 6) + (h << 5);
        const int rw0  = j * 64 + wave * 8;
        const int row0 = (rw0 & 31) + ((rw0 >> 5) << 6) + (h << 5);
        gload_lds16(g + (size_t)row * K + kcol + sch, lds + row0 * 64);
    }
}

__device__ __forceinline__ void load_afr(const __bf16* buf, int wm, int mh,
                                         int lr, int lq, bf16x8 (&af)[4][2]) {
#pragma unroll
    for (int mt = 0; mt < 4; mt++) {
        const __bf16* rp = buf + (wm * 128 + mh * 64 + mt * 16 + lr) * 64;
#pragma unroll
        for (int kk = 0; kk < 2; kk++)
            af[mt][kk] = *(const bf16x8*)(rp + (((kk * 4 + lq) ^ (lr & 7)) << 3));
    }
}
__device__ __forceinline__ void load_afr64(const __bf16* buf, int wm,
                                           int lr, int lq, bf16x8 (&af)[4][2]) {
#pragma unroll
    for (int mt = 0; mt < 4; mt++) {
        const __bf16* rp = buf + (wm * 64 + mt * 16 + lr) * 64;
#pragma unroll
        for (int kk = 0; kk < 2; kk++)
            af[mt][kk] = *(const bf16x8*)(rp + (((kk * 4 + lq) ^ (lr & 7)) << 3));
    }
}
__device__ __forceinline__ void load_bfr(const __bf16* buf, int wn, int nh,
                                         int lr, int lq, bf16x8 (&bf)[2][2]) {
#pragma unroll
    for (int nt = 0; nt < 2; nt++) {
        const __bf16* rp = buf + (wn * 64 + nh * 32 + nt * 16 + lr) * 64;
#pragma unroll
        for (int kk = 0; kk < 2; kk++)
            bf[nt][kk] = *(const bf16x8*)(rp + (((kk * 4 + lq) ^ (lr & 7)) << 3));
    }
}

#define MFMA_QUAD(MH, NH, AF, BF)                                              \
    _Pragma("unroll") for (int kk_ = 0; kk_ < 2; kk_++)                        \
    _Pragma("unroll") for (int mt_ = 0; mt_ < 4; mt_++)                        \
    _Pragma("unroll") for (int nt_ = 0; nt_ < 2; nt_++)                        \
        acc[(MH) * 4 + mt_][(NH) * 2 + nt_] =                                  \
            __builtin_amdgcn_mfma_f32_16x16x32_bf16(                           \
                AF[mt_][kk_], BF[nt_][kk_],                                    \
                acc[(MH) * 4 + mt_][(NH) * 2 + nt_], 0, 0, 0);

#define MFMA_Q128(NH, AF, BF)                                                  \
    _Pragma("unroll") for (int kk_ = 0; kk_ < 2; kk_++)                        \
    _Pragma("unroll") for (int mt_ = 0; mt_ < 4; mt_++)                        \
    _Pragma("unroll") for (int nt_ = 0; nt_ < 2; nt_++)                        \
        acc[mt_][(NH) * 2 + nt_] =                                             \
            __builtin_amdgcn_mfma_f32_16x16x32_bf16(                           \
                AF[mt_][kk_], BF[nt_][kk_],                                    \
                acc[mt_][(NH) * 2 + nt_], 0, 0, 0);

// ---------------------------------------------------------------- GEMM 256x256 (r5, best measured)
// 8 waves (2M x 4N), BK=64, 128 KiB LDS (double buffer), 4 phases/tile,
// pre-MFMA barriers only (post-MFMA barriers removed; hazards carried by
// {VMW + pre-MFMA barrier} pairs — measured +9% in r5).
// EPI: 0 = +bias -> bf16; 2 = +bias, GELU(logistic) -> bf16.
template <int EPI>
__device__ __forceinline__
void gemm_body(const __bf16* __restrict__ A, const __bf16* __restrict__ Bt,
               const float* __restrict__ bias, __bf16* __restrict__ Cb,
               int M, int N, int K) {
    __shared__ __bf16 smem[65536];
    __bf16* Ac = smem;
    __bf16* An = smem + 16384;
    __bf16* Bc = smem + 32768;
    __bf16* Bn = smem + 49152;

    const int tid  = threadIdx.x;
    const int wave = tid >> 6;
    const int lane = tid & 63;
    const int wm = wave >> 2, wn = wave & 3;
    const int lr = lane & 15, lq = lane >> 4;

    const int gx  = gridDim.x;
    const int nwg = gx * gridDim.y;
    const int orig = blockIdx.y * gx + blockIdx.x;
    const int q8 = nwg >> 3, r8 = nwg & 7;
    const int xcd = orig & 7, oi = orig >> 3;
    const int wgid = (xcd < r8 ? xcd * (q8 + 1) : r8 * (q8 + 1) + (xcd - r8) * q8) + oi;
    const int bm = wgid / gx, bn = wgid - bm * gx;

    const __bf16* gA = A  + (size_t)bm * 256 * K;
    const __bf16* gB = Bt + (size_t)bn * 256 * K;
    const int NT = K >> 6;

    floatx4 acc[8][4];
#pragma unroll
    for (int i = 0; i < 8; i++)
#pragma unroll
        for (int j = 0; j < 4; j++) acc[i][j] = (floatx4){0.f, 0.f, 0.f, 0.f};

    stage_A(gA, K, 0, Ac, 0, tid, wave);
    stage_B(gB, K, 0, Bc, 0, tid, wave);
    stage_B(gB, K, 0, Bc, 1, tid, wave);
    stage_A(gA, K, 0, Ac, 1, tid, wave);
    if (NT > 1) stage_A(gA, K, 64, An, 0, tid, wave);
    VMW(4);
    GBAR();

    bf16x8 af[4][2], b0[2][2], b1[2][2];

    for (int t = 0; t < NT; t++) {
        const int k1 = (t + 1) << 6;
        // phase 0: quad (mh0, nh0); stage B0(t+1)
        if (t == NT - 1) { VMW(0); } else { VMW(4); }
        if (t + 1 < NT) stage_B(gB, K, k1, Bn, 0, tid, wave);
        load_afr(Ac, wm, 0, lr, lq, af);
        load_bfr(Bc, wn, 0, lr, lq, b0);
        GBAR(); LGKM0(); SCHED0();
        __builtin_amdgcn_s_setprio(1);
        MFMA_QUAD(0, 0, af, b0);
        __builtin_amdgcn_s_setprio(0);
        // phase 1: quad (mh0, nh1); stage B1(t+1)
        VMW(4);
        if (t + 1 < NT) stage_B(gB, K, k1, Bn, 1, tid, wave);
        load_bfr(Bc, wn, 1, lr, lq, b1);
        GBAR(); LGKM0(); SCHED0();
        __builtin_amdgcn_s_setprio(1);
        MFMA_QUAD(0, 1, af, b1);
        __builtin_amdgcn_s_setprio(0);
        // phase 2: quad (mh1, nh1); stage A1(t+1)
        VMW(4);
        if (t + 1 < NT) stage_A(gA, K, k1, An, 1, tid, wave);
        load_afr(Ac, wm, 1, lr, lq, af);
        GBAR(); LGKM0(); SCHED0();
        __builtin_amdgcn_s_setprio(1);
        MFMA_QUAD(1, 1, af, b1);
        __builtin_amdgcn_s_setprio(0);
        // phase 3: quad (mh1, nh0); stage A0(t+2) into CURRENT A buffer
        VMW(4);
        if (t + 2 < NT) stage_A(gA, K, (t + 2) << 6, Ac, 0, tid, wave);
        GBAR();
        __builtin_amdgcn_s_setprio(1);
        MFMA_QUAD(1, 0, af, b0);
        __builtin_amdgcn_s_setprio(0);
        __bf16* ta = Ac; Ac = An; An = ta;
        __bf16* tb = Bc; Bc = Bn; Bn = tb;
    }

    // repack through LDS (reuse the 128 KiB as a [256][256] bf16 C-tile)
    GBAR();
    __bf16* Ct = smem;
#pragma unroll
    for (int m = 0; m < 8; m++)
#pragma unroll
        for (int n = 0; n < 4; n++) {
            const int col = wn * 64 + n * 16 + lr;
            const float bv = bias[bn * 256 + col];
#pragma unroll
            for (int r = 0; r < 4; r++) {
                float v = acc[m][n][r] + bv;
                if constexpr (EPI == 2) {
                    const float e = __expf(v * -1.702f);
                    v = v * fast_rcp(1.f + e);
                }
                Ct[(wm * 128 + m * 16 + lq * 4 + r) * 256 + col] = (__bf16)v;
            }
        }
    __syncthreads();
#pragma unroll
    for (int j = 0; j < 16; j++) {
        const int ci = j * 512 + tid;
        const int row = ci >> 5, ch = ci & 31;
        *(bf16x8*)(Cb + (size_t)(bm * 256 + row) * N + bn * 256 + ch * 8) =
            *(const bf16x8*)(Ct + row * 256 + ch * 8);
    }
}

// ---------------------------------------------------------------- GEMM 128x256 (tail fix)
// For the two 324-block-grid GEMMs (proj, ffn2): BM=128 -> 648 blocks (=81x8,
// XCD-divisible), makespan ~2.6 x (T/2) vs 2 x T.  8 waves 2M x 4N, per-wave
// 64x64, 2 phases/tile, A+B double-buffered in 96 KB.  Counted-vmcnt by
// induction: per tile t, issue A(t+1) @ph0, B0/B1(t+1) @ph1.  Entering ph0(t):
// outstanding = [A(t),B0(t),B1(t)] -> VMW(2) completes A,B0; GBAR publishes;
// ph1: outstanding [B1(t),A(t+1)] -> VMW(2) completes B1 (VMW(0) last tile).
// Overwrite hazards: A(t+1) targets the buffer whose reads retired at
// LGKM0(ph0,t-1) before GBAR(ph1,t-1), which every wave passed; B(t+1) targets
// buffers whose reads retired before GBAR(ph0,t).  EPI 3/4 only (direct
// stores, no LDS repack).
template <int EPI>
__device__ __forceinline__
void gemm_body128(const __bf16* __restrict__ A, const __bf16* __restrict__ Bt,
                  const float* __restrict__ bias, const float* __restrict__ res,
                  float* __restrict__ Cf, int M, int N, int K,
                  const int* __restrict__ prm) {
    __shared__ __bf16 smem[49152];   // A dbuf 2x16KB | B dbuf 2x32KB = 96 KB
    __bf16* Ac = smem;
    __bf16* An = smem + 8192;
    __bf16* Bc = smem + 16384;
    __bf16* Bn = smem + 32768;

    const int tid  = threadIdx.x;
    const int wave = tid >> 6;
    const int lane = tid & 63;
    const int wm = wave >> 2, wn = wave & 3;
    const int lr = lane & 15, lq = lane >> 4;

    const int gx  = gridDim.x;
    const int nwg = gx * gridDim.y;
    const int orig = blockIdx.y * gx + blockIdx.x;
    const int q8 = nwg >> 3, r8 = nwg & 7;
    const int xcd = orig & 7, oi = orig >> 3;
    const int wgid = (xcd < r8 ? xcd * (q8 + 1) : r8 * (q8 + 1) + (xcd - r8) * q8) + oi;
    const int bm = wgid / gx, bn = wgid - bm * gx;

    const __bf16* gA = A  + (size_t)bm * 128 * K;
    const __bf16* gB = Bt + (size_t)bn * 256 * K;
    const int NT = K >> 6;   // 8 (proj) or 32 (ffn2)

    floatx4 acc[4][4];
#pragma unroll
    for (int i = 0; i < 4; i++)
#pragma unroll
        for (int j = 0; j < 4; j++) acc[i][j] = (floatx4){0.f, 0.f, 0.f, 0.f};

    // prologue: A(0), B0(0), B1(0) — matches steady-state queue order
    stage_A128(gA, K, 0, Ac, tid, wave);
    stage_B(gB, K, 0, Bc, 0, tid, wave);
    stage_B(gB, K, 0, Bc, 1, tid, wave);

    bf16x8 af[4][2], b0[2][2], b1[2][2];

    for (int t = 0; t < NT; t++) {
        const int k1 = (t + 1) << 6;
        // ---- phase 0: quad nh0.  VMW(2) completes A(t),B0(t) (leaves B1);
        //      stage A(t+1); GBAR publishes; read af + b0.
        VMW(2);
        if (t + 1 < NT) stage_A128(gA, K, k1, An, tid, wave);
        GBAR();
        load_afr64(Ac, wm, lr, lq, af);
        load_bfr(Bc, wn, 0, lr, lq, b0);
        LGKM0(); SCHED0();
        __builtin_amdgcn_s_setprio(1);
        MFMA_Q128(0, af, b0);
        __builtin_amdgcn_s_setprio(0);
        // ---- phase 1: quad nh1.  VMW completes B1(t) (leaves A(t+1) unless
        //      last tile); stage B0/B1(t+1); GBAR publishes; read b1.
        if (t == NT - 1) { VMW(0); } else { VMW(2); }
        if (t + 1 < NT) {
            stage_B(gB, K, k1, Bn, 0, tid, wave);
            stage_B(gB, K, k1, Bn, 1, tid, wave);
        }
        GBAR();
        load_bfr(Bc, wn, 1, lr, lq, b1);
        LGKM0(); SCHED0();
        __builtin_amdgcn_s_setprio(1);
        MFMA_Q128(1, af, b1);
        __builtin_amdgcn_s_setprio(0);
        // swap double buffers
        __bf16* ta = Ac; Ac = An; An = ta;
        __bf16* tb = Bc; Bc = Bn; Bn = tb;
    }

    // direct f32 epilogue (EPI 3 = in-place residual, 4 = gathered residual)
#pragma unroll
    for (int m = 0; m < 4; m++) {
        const int row = bm * 128 + wm * 64 + m * 16 + lq * 4;
        int tok[4];
        if constexpr (EPI == 4) {
#pragma unroll
            for (int r = 0; r < 4; r++) tok[r] = prm[row + r];
        }
#pragma unroll
        for (int n = 0; n < 4; n++) {
            const int col = bn * 256 + wn * 64 + n * 16 + lr;
            const float bv = bias[col];
#pragma unroll
            for (int r = 0; r < 4; r++) {
                const float v = acc[m][n][r] + bv;
                if constexpr (EPI == 3) {
                    const size_t off = (size_t)(row + r) * N + col;
                    Cf[off] = res[off] + v;
                } else {  // EPI == 4
                    const size_t off = (size_t)tok[r] * N + col;
                    Cf[off] = res[off] + v;
                }
            }
        }
    }
}

// Distinct names per stage so the profiler shows the true split.
__global__ __launch_bounds__(512, 2)
void gemm_qkv(const __bf16* __restrict__ A, const __bf16* __restrict__ Bt,
              const float* __restrict__ bias, __bf16* __restrict__ Cb, int N, int K) {
    gemm_body<0>(A, Bt, bias, Cb, NTOK, N, K);
}
__global__ __launch_bounds__(512, 2)
void gemm_ffn1(const __bf16* __restrict__ A, const __bf16* __restrict__ Bt,
               const float* __restrict__ bias, __bf16* __restrict__ Cb, int N, int K) {
    gemm_body<2>(A, Bt, bias, Cb, NTOK, N, K);
}
__global__ __launch_bounds__(512, 2)
void gemm_proj(const __bf16* __restrict__ A, const __bf16* __restrict__ Bt,
               const float* __restrict__ bias, const float* __restrict__ res,
               float* __restrict__ Cf, const int* __restrict__ prm, int N, int K) {
    gemm_body128<4>(A, Bt, bias, res, Cf, NTOK, N, K, prm);
}
__global__ __launch_bounds__(512, 2)
void gemm_ffn2(const __bf16* __restrict__ A, const __bf16* __restrict__ Bt,
               const float* __restrict__ bias, const float* __restrict__ res,
               float* __restrict__ Cf, int N, int K) {
    gemm_body128<3>(A, Bt, bias, res, Cf, NTOK, N, K, nullptr);
}

// ---------------------------------------------------------------- attention (MFMA)
__global__ __launch_bounds__(256)
void attn_mfma(const __bf16* __restrict__ qkv, __bf16* __restrict__ aout,
               const float* __restrict__ rel_bias) {
    __shared__ __bf16 vsT[HD * WS];      // [d][key-swizzled], 32 KB
    __shared__ __bf16 pbuf[4][64][34];   // wave-private P tile
    const int w = blockIdx.x, h = blockIdx.y;
    const int tid = threadIdx.x;
    const int wave = tid >> 6, lane = tid & 63;
    const int lr = lane & 15, lq = lane >> 4;
    const size_t base = (size_t)w * (WS * 1536) + h * 64;

    for (int c = tid; c < WS * 8; c += 256) {
        const int key = c >> 3, d8 = c & 7;
        bf16x8 vv = *(const bf16x8*)(qkv + base + 1024 + (size_t)key * 1536 + d8 * 8);
#pragma unroll
        for (int jj = 0; jj < 8; jj++) {
            const int d = d8 * 8 + jj;
            vsT[d * WS + (((key >> 3) ^ (d & 31)) << 3) + (key & 7)] = vv[jj];
        }
    }

    const int q0 = wave * 64;
    bf16x8 qf[4][2];
#pragma unroll
    for (int mt = 0; mt < 4; mt++)
#pragma unroll
        for (int kk = 0; kk < 2; kk++)
            qf[mt][kk] = *(const bf16x8*)(qkv + base +
                (size_t)(q0 + mt * 16 + lr) * 1536 + kk * 32 + lq * 8);

    __syncthreads();   // the only block-wide barrier

    floatx4 o[4][4];
    float lsum[4][4];
#pragma unroll
    for (int mt = 0; mt < 4; mt++)
#pragma unroll
        for (int dt = 0; dt < 4; dt++) o[mt][dt] = (floatx4){0.f, 0.f, 0.f, 0.f};
#pragma unroll
    for (int mt = 0; mt < 4; mt++)
#pragma unroll
        for (int r = 0; r < 4; r++) lsum[mt][r] = 0.f;

    const float sc = 0.125f * 1.44269504089f;
    const float bb = rel_bias[h] * 1.44269504089f;
    const __bf16* kp0 = qkv + base + 512;

    bf16x8 kc[2][2];
#pragma unroll
    for (int nt = 0; nt < 2; nt++) {
        const __bf16* kp = kp0 + (size_t)(nt * 16 + lr) * 1536 + lq * 8;
        kc[nt][0] = *(const bf16x8*)(kp);
        kc[nt][1] = *(const bf16x8*)(kp + 32);
    }

    for (int kt = 0; kt < 8; kt++) {
        const int kbase = kt * 32;
        bf16x8 kn[2][2];
        if (kt < 7) {
#pragma unroll
            for (int nt = 0; nt < 2; nt++) {
                const __bf16* kp = kp0 + (size_t)(kbase + 32 + nt * 16 + lr) * 1536 + lq * 8;
                kn[nt][0] = *(const bf16x8*)(kp);
                kn[nt][1] = *(const bf16x8*)(kp + 32);
            }
        }
        floatx4 s[4][2];
#pragma unroll
        for (int mt = 0; mt < 4; mt++)
#pragma unroll
            for (int nt = 0; nt < 2; nt++) s[mt][nt] = (floatx4){0.f, 0.f, 0.f, 0.f};
#pragma unroll
        for (int nt = 0; nt < 2; nt++)
#pragma unroll
            for (int mt = 0; mt < 4; mt++) {
                s[mt][nt] = __builtin_amdgcn_mfma_f32_16x16x32_bf16(qf[mt][0], kc[nt][0], s[mt][nt], 0, 0, 0);
                s[mt][nt] = __builtin_amdgcn_mfma_f32_16x16x32_bf16(qf[mt][1], kc[nt][1], s[mt][nt], 0, 0, 0);
            }
#pragma unroll
        for (int mt = 0; mt < 4; mt++)
#pragma unroll
            for (int nt = 0; nt < 2; nt++)
#pragma unroll
                for (int r = 0; r < 4; r++) {
                    float e = exp2f(s[mt][nt][r] * sc + bb);
                    lsum[mt][r] += e;
                    pbuf[wave][mt * 16 + lq * 4 + r][nt * 16 + lr] = (__bf16)e;
                }
        bf16x8 vf[4];
#pragma unroll
        for (int dt = 0; dt < 4; dt++) {
            const int d = dt * 16 + lr;
            vf[dt] = *(const bf16x8*)(vsT + d * WS +
                                      (((kt * 4 + lq) ^ (d & 31)) << 3));
        }
#pragma unroll
        for (int mt = 0; mt < 4; mt++) {
            bf16x8 pf = *(const bf16x8*)(&pbuf[wave][mt * 16 + lr][lq * 8]);
#pragma unroll
            for (int dt = 0; dt < 4; dt++)
                o[mt][dt] = __builtin_amdgcn_mfma_f32_16x16x32_bf16(pf, vf[dt], o[mt][dt], 0, 0, 0);
        }
#pragma unroll
        for (int nt = 0; nt < 2; nt++) { kc[nt][0] = kn[nt][0]; kc[nt][1] = kn[nt][1]; }
    }

#pragma unroll
    for (int mt = 0; mt < 4; mt++)
#pragma unroll
        for (int r = 0; r < 4; r++) {
            float v = lsum[mt][r];
            v += __shfl_xor(v, 1); v += __shfl_xor(v, 2);
            v += __shfl_xor(v, 4); v += __shfl_xor(v, 8);
            lsum[mt][r] = fast_rcp(v);
        }

#pragma unroll
    for (int dh = 0; dh < 2; dh++) {
#pragma unroll
        for (int mt = 0; mt < 4; mt++)
#pragma unroll
            for (int dt = 0; dt < 2; dt++)
#pragma unroll
                for (int r = 0; r < 4; r++)
                    pbuf[wave][mt * 16 + lq * 4 + r][dt * 16 + lr] =
                        (__bf16)(o[mt][dh * 2 + dt][r] * lsum[mt][r]);
#pragma unroll
        for (int it = 0; it < 4; it++) {
            const int c = it * 64 + lane;
            const int row = c >> 2, seg = c & 3;
            bf16x8 val = *(const bf16x8*)(&pbuf[wave][row][seg * 8]);
            *(bf16x8*)(aout + (size_t)(w * WS + q0 + row) * CC + h * 64 + dh * 32 + seg * 8) = val;
        }
    }
}

// ---------------------------------------------------------------- launch
extern "C" void kernel_launch(void* const* d_in, const int* in_sizes, int n_in,
                              void* d_out, int out_size, void* d_ws, size_t ws_size,
                              hipStream_t stream) {
    const float* x      = (const float*)d_in[0];
    const float* mesh   = (const float*)d_in[1];
    const float* ln1_g  = (const float*)d_in[2];
    const float* ln1_b  = (const float*)d_in[3];
    const float* qkv_w  = (const float*)d_in[4];
    const float* qkv_b  = (const float*)d_in[5];
    const float* rel_b  = (const float*)d_in[6];
    const float* proj_w = (const float*)d_in[7];
    const float* proj_b = (const float*)d_in[8];
    const float* ln2_g  = (const float*)d_in[9];
    const float* ln2_b  = (const float*)d_in[10];
    const float* w1     = (const float*)d_in[11];
    const float* b1     = (const float*)d_in[12];
    const float* w2     = (const float*)d_in[13];
    const float* b2     = (const float*)d_in[14];
    const int*   wid    = (const int*)d_in[15];

    char* ws = (char*)d_ws;
    int*    perm  = (int*)(ws + 0);
    __bf16* wqkv  = (__bf16*)(ws + 331776);
    __bf16* wproj = (__bf16*)(ws + 1904640);
    __bf16* w1t   = (__bf16*)(ws + 2428928);
    __bf16* w2t   = (__bf16*)(ws + 4526080);
    const size_t BB = 6623232;
    __bf16* hln1 = (__bf16*)(ws + BB);
    __bf16* qkv  = (__bf16*)(ws + BB + 42467328);
    __bf16* aout = (__bf16*)(ws + BB + 169869312);
    __bf16* h2   = (__bf16*)(ws + BB + 84934656);
    __bf16* f1   = (__bf16*)(ws + BB + 127401984);
    float*  xout = (float*)d_out;
    int*    counters = (int*)aout;   // dead region until attention writes aout

    hipMemsetAsync(counters, 0, NW * sizeof(int), stream);
    build_perm_atomic<<<NTOK / 256, 256, 0, stream>>>(wid, perm, counters);

    transpose_bf16<<<(512 * 1536 + 255) / 256, 256, 0, stream>>>(qkv_w, wqkv, 512, 1536);
    transpose_bf16<<<(512 * 512 + 255) / 256, 256, 0, stream>>>(proj_w, wproj, 512, 512);
    transpose_bf16<<<(512 * 2048 + 255) / 256, 256, 0, stream>>>(w1, w1t, 512, 2048);
    transpose_bf16<<<(2048 * 512 + 255) / 256, 256, 0, stream>>>(w2, w2t, 2048, 512);

    ln1_gather<<<NTOK, 64, 0, stream>>>(x, perm, ln1_g, ln1_b, hln1);

    gemm_qkv<<<dim3(1536 / 256, NTOK / 256), 512, 0, stream>>>(
        hln1, wqkv, qkv_b, qkv, 1536, 512);

    attn_mfma<<<dim3(NW, NH), 256, 0, stream>>>(qkv, aout, rel_b);

    // proj with fused gathered residual: xout[perm[row]] = x[perm[row]] + out
    gemm_proj<<<dim3(512 / 256, NTOK / 128), 512, 0, stream>>>(
        aout, wproj, proj_b, x, xout, perm, 512, 512);

    ln2_only<<<NTOK, 64, 0, stream>>>(xout, ln2_g, ln2_b, h2);

    gemm_ffn1<<<dim3(2048 / 256, NTOK / 256), 512, 0, stream>>>(
        h2, w1t, b1, f1, 2048, 512);

    gemm_ffn2<<<dim3(512 / 256, NTOK / 128), 512, 0, stream>>>(
        f1, w2t, b2, xout, xout, 512, 2048);

    hipMemcpyAsync((char*)d_out + (size_t)NTOK * CC * 4, mesh,
                   (size_t)NTOK * 3 * 4, hipMemcpyDeviceToDevice, stream);
}